// Round 2
// baseline (73.646 us; speedup 1.0000x reference)
//
#include <hip/hip_runtime.h>

#define HW  (1024u*1024u)
#define CHW (2u*HW)
#define MAXP 65536u

// Output layout (float32): [coords 8*65536*2][labels 8*65536][scores 8*65536]
#define COORD_FLOATS 1048576u
#define LABEL_OFF    1048576u
#define SCORE_OFF    1572864u

// ---- k0: fill output: coords = -1.0f, labels/scores = 0.0f ----
__global__ __launch_bounds__(256) void fill_out(float* __restrict__ out) {
    int i = blockIdx.x * 256 + threadIdx.x;          // 0..524287 float4s
    float v = (i < (int)(COORD_FLOATS / 4)) ? -1.0f : 0.0f;
    float4 f; f.x = f.y = f.z = f.w = v;
    ((float4*)out)[i] = f;
}

// ---- k1: 7x7 NMS mask, 64x64 tile + halo 3, separable max, ballot -> bitmask ----
__global__ __launch_bounds__(256) void mask_kernel(const float* __restrict__ map,
                                                   unsigned long long* __restrict__ bits) {
    __shared__ float sIn[70][72];
    __shared__ float sRow[70][64];
    int bid = blockIdx.x;
    int tileX = bid & 15, tileY = (bid >> 4) & 15, c = (bid >> 8) & 1, b = bid >> 9;
    const float* base = map + ((size_t)(b * 2 + c) << 20);
    int h0 = tileY * 64 - 3, w0 = tileX * 64 - 3;
    int tid = threadIdx.x;

    for (int idx = tid; idx < 70 * 70; idx += 256) {
        int r = idx / 70, cc = idx - r * 70;
        int gh = h0 + r, gw = w0 + cc;
        float v = -3.0e38f;
        if ((unsigned)gh < 1024u && (unsigned)gw < 1024u) v = base[gh * 1024 + gw];
        sIn[r][cc] = v;
    }
    __syncthreads();

    for (int idx = tid; idx < 70 * 64; idx += 256) {
        int r = idx >> 6, w = idx & 63;
        float m = sIn[r][w];
        m = fmaxf(m, sIn[r][w + 1]);
        m = fmaxf(m, sIn[r][w + 2]);
        m = fmaxf(m, sIn[r][w + 3]);
        m = fmaxf(m, sIn[r][w + 4]);
        m = fmaxf(m, sIn[r][w + 5]);
        m = fmaxf(m, sIn[r][w + 6]);
        sRow[r][w] = m;
    }
    __syncthreads();

    int w = tid & 63, wv = tid >> 6;
    int gw = tileX * 64 + w;
    for (int rr = wv; rr < 64; rr += 4) {
        float v = sIn[rr + 3][w + 3];
        float m = sRow[rr][w];
        m = fmaxf(m, sRow[rr + 1][w]);
        m = fmaxf(m, sRow[rr + 2][w]);
        m = fmaxf(m, sRow[rr + 3][w]);
        m = fmaxf(m, sRow[rr + 4][w]);
        m = fmaxf(m, sRow[rr + 5][w]);
        m = fmaxf(m, sRow[rr + 6][w]);
        int gh = tileY * 64 + rr;
        bool flag = (v == m) && (v > 0.5f) &&
                    (gh >= 6) && (gh <= 1017) && (gw >= 6) && (gw <= 1017);
        unsigned long long bm = __ballot(flag);
        if (w == 0) {
            // word index: b*32768 + c*16384 + gh*16 + tileX
            bits[((size_t)b << 15) + ((size_t)c << 14) + ((size_t)gh << 4) + tileX] = bm;
        }
    }
}

// ---- k2a: per-chunk popcount (chunk = 256 u64 words = 16384 bits) ----
__global__ __launch_bounds__(256) void count_kernel(const unsigned long long* __restrict__ bits,
                                                    unsigned* __restrict__ chunkCount) {
    int blk = blockIdx.x;                       // b*128 + chunk, 0..1023
    int tid = threadIdx.x;
    unsigned long long wd = bits[(size_t)blk * 256 + tid];
    int cnt = __popcll(wd);
    for (int off = 32; off; off >>= 1) cnt += __shfl_down(cnt, off, 64);
    __shared__ int s[4];
    if ((tid & 63) == 0) s[tid >> 6] = cnt;
    __syncthreads();
    if (tid == 0) chunkCount[blk] = (unsigned)(s[0] + s[1] + s[2] + s[3]);
}

// ---- k2b: per-batch exclusive scan over 128 chunk counts ----
__global__ __launch_bounds__(128) void scan_kernel(const unsigned* __restrict__ chunkCount,
                                                   unsigned* __restrict__ chunkBase) {
    int b = blockIdx.x, t = threadIdx.x;        // 8 blocks x 128 threads
    __shared__ unsigned s[128];
    unsigned v = chunkCount[b * 128 + t];
    s[t] = v;
    __syncthreads();
    for (int off = 1; off < 128; off <<= 1) {
        unsigned add = (t >= off) ? s[t - off] : 0u;
        __syncthreads();
        s[t] += add;
        __syncthreads();
    }
    chunkBase[b * 128 + t] = s[t] - v;          // exclusive prefix
}

// ---- k3: ordered scatter of peaks (float32 outputs) ----
__global__ __launch_bounds__(256) void scatter_kernel(const float* __restrict__ map,
                                                      const unsigned long long* __restrict__ bits,
                                                      const unsigned* __restrict__ chunkBase,
                                                      float* __restrict__ out) {
    int blk = blockIdx.x;                       // b*128 + chunk
    int b = blk >> 7;
    int tid = threadIdx.x;
    unsigned long long wd = bits[(size_t)blk * 256 + tid];
    int cnt = __popcll(wd);
    __shared__ int s[256];
    s[tid] = cnt;
    __syncthreads();
    for (int off = 1; off < 256; off <<= 1) {
        int add = (tid >= off) ? s[tid - off] : 0;
        __syncthreads();
        s[tid] += add;
        __syncthreads();
    }
    unsigned base = chunkBase[blk] + (unsigned)(s[tid] - cnt);
    unsigned wib = ((unsigned)(blk & 127)) * 256u + (unsigned)tid;  // word idx in batch

    unsigned long long m = wd;
    unsigned n = 0;
    while (m) {
        int bit = __builtin_ctzll(m);
        m &= m - 1;
        unsigned slot = base + n;
        n++;
        if (slot < MAXP) {
            unsigned flat = wib * 64u + (unsigned)bit;   // < 2^21
            unsigned c = flat >> 20;
            unsigned h = (flat >> 10) & 1023u;
            unsigned w = flat & 1023u;
            float score = map[(size_t)b * CHW + flat];
            unsigned o = b * MAXP + slot;
            out[2u * o]         = (float)w;              // x
            out[2u * o + 1]     = (float)h;              // y
            out[LABEL_OFF + o]  = (float)(c + 1u);       // label
            out[SCORE_OFF + o]  = score;                 // score
        }
    }
}

extern "C" void kernel_launch(void* const* d_in, const int* in_sizes, int n_in,
                              void* d_out, int out_size, void* d_ws, size_t ws_size,
                              hipStream_t stream) {
    const float* map = (const float*)d_in[0];
    float* out = (float*)d_out;
    unsigned long long* bits = (unsigned long long*)d_ws;            // 262144 u64 = 2 MB
    unsigned* chunkCount = (unsigned*)((char*)d_ws + 2097152);       // 1024 u32
    unsigned* chunkBase  = chunkCount + 1024;                        // 1024 u32

    fill_out<<<2048, 256, 0, stream>>>(out);
    mask_kernel<<<4096, 256, 0, stream>>>(map, bits);
    count_kernel<<<1024, 256, 0, stream>>>(bits, chunkCount);
    scan_kernel<<<8, 128, 0, stream>>>(chunkCount, chunkBase);
    scatter_kernel<<<1024, 256, 0, stream>>>(map, bits, chunkBase, out);
}

// Round 3
// 45.471 us; speedup vs baseline: 1.6196x; 1.6196x over previous
//
#include <hip/hip_runtime.h>

#define HW  (1024u*1024u)
#define CHW (2u*HW)
#define MAXP 65536u
#define LABEL_OFF 1048576u
#define SCORE_OFF 1572864u

#define NINF (-3.0e38f)

__device__ __forceinline__ float max3f(float a, float b, float c) {
    return fmaxf(fmaxf(a, b), c);
}

// spread low 16 bits of x to every 4th bit position (bit i -> bit 4i)
__device__ __forceinline__ unsigned long long spread4(unsigned long long x) {
    x &= 0xFFFFull;
    x = (x | (x << 24)) & 0x000000FF000000FFull;
    x = (x | (x << 12)) & 0x000F000F000F000Full;
    x = (x | (x << 6))  & 0x0303030303030303ull;
    x = (x | (x << 3))  & 0x1111111111111111ull;
    return x;
}

// ---- k0: fill output: coords = -1.0f, labels/scores = 0.0f ----
__global__ __launch_bounds__(256) void fill_out(float* __restrict__ out) {
    int i = blockIdx.x * 256 + threadIdx.x;
    float v = (i < 262144) ? -1.0f : 0.0f;   // 262144 float4 = coords region
    float4 f; f.x = f.y = f.z = f.w = v;
    ((float4*)out)[i] = f;
}

// ---- k1: 7x7 NMS mask, register rolling window + 1-row LDS exchange ----
// block: 256 threads, thread t owns cols 4t..4t+3 (float4), 16 output rows/block
// grid: 16 images * 64 stripes = 1024 blocks
__global__ __launch_bounds__(256) void mask_kernel(const float* __restrict__ map,
                                                   unsigned long long* __restrict__ bits) {
    __shared__ float4 rowbuf[2][258];
    int bid = blockIdx.x;
    int stripe = bid & 63;
    int img = bid >> 6;                       // b*2 + c
    int r0 = stripe << 4;
    int tid = threadIdx.x;
    int lane = tid & 63, wv = tid >> 6;
    const float4* __restrict__ base = (const float4*)(map + ((size_t)img << 20));

    if (tid < 2) {
        float4 ninf4 = make_float4(NINF, NINF, NINF, NINF);
        rowbuf[0][tid * 257] = ninf4;         // [0] and [257] pads
        rowbuf[1][tid * 257] = ninf4;
    }

    // column-validity nibble (cols 6..1017 valid)
    int c0 = tid * 4;
    int cvm = 0;
    #pragma unroll
    for (int j = 0; j < 4; ++j) {
        int cc = c0 + j;
        if (cc >= 6 && cc <= 1017) cvm |= (1 << j);
    }

    // rolling window: slot(input row r0+j) = (j+3)&7 ; preload j=-3..3
    float4 w[8];
    #pragma unroll
    for (int k = 0; k < 7; ++k) {
        int rr = r0 - 3 + k;
        w[k] = (rr >= 0) ? base[rr * 256 + tid] : make_float4(NINF, NINF, NINF, NINF);
    }

    #pragma unroll 1
    for (int ii = 0; ii < 2; ++ii) {
        #pragma unroll
        for (int jj = 0; jj < 8; ++jj) {
            int gh = r0 + ii * 8 + jj;
            // prefetch input row gh+4 into slot (jj+7)&7 (used next iteration)
            {
                int lr = gh + 4;
                w[(jj + 7) & 7] = (lr <= 1023) ? base[lr * 256 + tid]
                                               : make_float4(NINF, NINF, NINF, NINF);
            }
            // vertical 7-max over slots jj..jj+6
            float4 s0 = w[(jj + 0) & 7], s1 = w[(jj + 1) & 7], s2 = w[(jj + 2) & 7];
            float4 s3 = w[(jj + 3) & 7], s4 = w[(jj + 4) & 7], s5 = w[(jj + 5) & 7];
            float4 s6 = w[(jj + 6) & 7];
            float4 vm;
            vm.x = max3f(max3f(s0.x, s1.x, s2.x), max3f(s3.x, s4.x, s5.x), s6.x);
            vm.y = max3f(max3f(s0.y, s1.y, s2.y), max3f(s3.y, s4.y, s5.y), s6.y);
            vm.z = max3f(max3f(s0.z, s1.z, s2.z), max3f(s3.z, s4.z, s5.z), s6.z);
            vm.w = max3f(max3f(s0.w, s1.w, s2.w), max3f(s3.w, s4.w, s5.w), s6.w);

            rowbuf[jj & 1][tid + 1] = vm;
            __syncthreads();
            float4 L = rowbuf[jj & 1][tid];
            float4 R = rowbuf[jj & 1][tid + 2];

            // horizontal 7-max for cols 4t..4t+3
            float m0 = max3f(max3f(L.y, L.z, L.w),  max3f(vm.x, vm.y, vm.z), vm.w);
            float m1 = max3f(max3f(L.z, L.w, vm.x), max3f(vm.y, vm.z, vm.w), R.x);
            float m2 = max3f(max3f(L.w, vm.x, vm.y), max3f(vm.z, vm.w, R.x), R.y);
            float m3 = max3f(max3f(vm.x, vm.y, vm.z), max3f(vm.w, R.x, R.y), R.z);

            float4 ctr = s3;                   // original row gh (slot jj+3)
            int rowok = (gh >= 6) & (gh <= 1017);
            int f0 = (ctr.x == m0) & (ctr.x > 0.5f) & ((cvm >> 0) & 1) & rowok;
            int f1 = (ctr.y == m1) & (ctr.y > 0.5f) & ((cvm >> 1) & 1) & rowok;
            int f2 = (ctr.z == m2) & (ctr.z > 0.5f) & ((cvm >> 2) & 1) & rowok;
            int f3 = (ctr.w == m3) & (ctr.w > 0.5f) & ((cvm >> 3) & 1) & rowok;

            unsigned long long B0 = __ballot(f0);
            unsigned long long B1 = __ballot(f1);
            unsigned long long B2 = __ballot(f2);
            unsigned long long B3 = __ballot(f3);
            if (lane < 4) {
                unsigned long long word =  spread4(B0 >> (16 * lane))
                                        | (spread4(B1 >> (16 * lane)) << 1)
                                        | (spread4(B2 >> (16 * lane)) << 2)
                                        | (spread4(B3 >> (16 * lane)) << 3);
                // word index: img*16384 + gh*16 + (wv*4 + lane)
                bits[((size_t)img << 14) + ((size_t)gh << 4) + (wv * 4 + lane)] = word;
            }
        }
    }
}

// ---- k2a: per-chunk popcount (chunk = 256 u64 words = 16384 bits) ----
__global__ __launch_bounds__(256) void count_kernel(const unsigned long long* __restrict__ bits,
                                                    unsigned* __restrict__ chunkCount) {
    int blk = blockIdx.x;                       // b*128 + chunk, 0..1023
    int tid = threadIdx.x;
    unsigned long long wd = bits[(size_t)blk * 256 + tid];
    int cnt = __popcll(wd);
    for (int off = 32; off; off >>= 1) cnt += __shfl_down(cnt, off, 64);
    __shared__ int s[4];
    if ((tid & 63) == 0) s[tid >> 6] = cnt;
    __syncthreads();
    if (tid == 0) chunkCount[blk] = (unsigned)(s[0] + s[1] + s[2] + s[3]);
}

// ---- k2b: per-batch exclusive scan over 128 chunk counts ----
__global__ __launch_bounds__(128) void scan_kernel(const unsigned* __restrict__ chunkCount,
                                                   unsigned* __restrict__ chunkBase) {
    int b = blockIdx.x, t = threadIdx.x;        // 8 blocks x 128 threads
    __shared__ unsigned s[128];
    unsigned v = chunkCount[b * 128 + t];
    s[t] = v;
    __syncthreads();
    for (int off = 1; off < 128; off <<= 1) {
        unsigned add = (t >= off) ? s[t - off] : 0u;
        __syncthreads();
        s[t] += add;
        __syncthreads();
    }
    chunkBase[b * 128 + t] = s[t] - v;          // exclusive prefix
}

// ---- k3: ordered scatter of peaks (float32 outputs) ----
__global__ __launch_bounds__(256) void scatter_kernel(const float* __restrict__ map,
                                                      const unsigned long long* __restrict__ bits,
                                                      const unsigned* __restrict__ chunkBase,
                                                      float* __restrict__ out) {
    int blk = blockIdx.x;                       // b*128 + chunk
    int b = blk >> 7;
    int tid = threadIdx.x;
    unsigned long long wd = bits[(size_t)blk * 256 + tid];
    int cnt = __popcll(wd);
    __shared__ int s[256];
    s[tid] = cnt;
    __syncthreads();
    for (int off = 1; off < 256; off <<= 1) {
        int add = (tid >= off) ? s[tid - off] : 0;
        __syncthreads();
        s[tid] += add;
        __syncthreads();
    }
    unsigned base = chunkBase[blk] + (unsigned)(s[tid] - cnt);
    unsigned wib = ((unsigned)(blk & 127)) * 256u + (unsigned)tid;  // word idx in batch

    unsigned long long m = wd;
    unsigned n = 0;
    while (m) {
        int bit = __builtin_ctzll(m);
        m &= m - 1;
        unsigned slot = base + n;
        n++;
        if (slot < MAXP) {
            unsigned flat = wib * 64u + (unsigned)bit;   // < 2^21
            unsigned c = flat >> 20;
            unsigned h = (flat >> 10) & 1023u;
            unsigned w = flat & 1023u;
            float score = map[(size_t)b * CHW + flat];
            unsigned o = b * MAXP + slot;
            out[2u * o]         = (float)w;              // x
            out[2u * o + 1]     = (float)h;              // y
            out[LABEL_OFF + o]  = (float)(c + 1u);       // label
            out[SCORE_OFF + o]  = score;                 // score
        }
    }
}

extern "C" void kernel_launch(void* const* d_in, const int* in_sizes, int n_in,
                              void* d_out, int out_size, void* d_ws, size_t ws_size,
                              hipStream_t stream) {
    const float* map = (const float*)d_in[0];
    float* out = (float*)d_out;
    unsigned long long* bits = (unsigned long long*)d_ws;            // 262144 u64 = 2 MB
    unsigned* chunkCount = (unsigned*)((char*)d_ws + 2097152);       // 1024 u32
    unsigned* chunkBase  = chunkCount + 1024;                        // 1024 u32

    fill_out<<<2048, 256, 0, stream>>>(out);
    mask_kernel<<<1024, 256, 0, stream>>>(map, bits);
    count_kernel<<<1024, 256, 0, stream>>>(bits, chunkCount);
    scan_kernel<<<8, 128, 0, stream>>>(chunkCount, chunkBase);
    scatter_kernel<<<1024, 256, 0, stream>>>(map, bits, chunkBase, out);
}

// Round 4
// 41.515 us; speedup vs baseline: 1.7740x; 1.0953x over previous
//
#include <hip/hip_runtime.h>

#define HW  (1024u*1024u)
#define CHW (2u*HW)
#define MAXP 65536u
#define LABEL_OFF 1048576u
#define SCORE_OFF 1572864u

#define NINF (-3.0e38f)

__device__ __forceinline__ float max3f(float a, float b, float c) {
    return fmaxf(fmaxf(a, b), c);
}

// spread low 16 bits of x to every 4th bit position (bit i -> bit 4i)
__device__ __forceinline__ unsigned long long spread4(unsigned long long x) {
    x &= 0xFFFFull;
    x = (x | (x << 24)) & 0x000000FF000000FFull;
    x = (x | (x << 12)) & 0x000F000F000F000Full;
    x = (x | (x << 6))  & 0x0303030303030303ull;
    x = (x | (x << 3))  & 0x1111111111111111ull;
    return x;
}

// ---- A: fused fill + 7x7 NMS mask + per-chunk count ----
// blocks 0..2047: fill d_out (coords=-1, labels/scores=0)
// blocks 2048..3071: mask; block = one 16-row stripe of one image = one chunk
__global__ __launch_bounds__(256) void fused_mask(const float* __restrict__ map,
                                                  unsigned long long* __restrict__ bits,
                                                  unsigned* __restrict__ chunkCount,
                                                  float* __restrict__ out) {
    int bid = blockIdx.x;
    int tid = threadIdx.x;

    if (bid < 2048) {                          // ---- fill part ----
        int i = bid * 256 + tid;
        float v = (i < 262144) ? -1.0f : 0.0f; // 262144 float4 = coords region
        float4 f; f.x = f.y = f.z = f.w = v;
        ((float4*)out)[i] = f;
        return;
    }

    // ---- mask part ----
    __shared__ float4 rowbuf[2][258];
    __shared__ int sred[4];
    int mbid = bid - 2048;
    int stripe = mbid & 63;
    int img = mbid >> 6;                      // b*2 + c
    int r0 = stripe << 4;
    int lane = tid & 63, wv = tid >> 6;
    const float4* __restrict__ base = (const float4*)(map + ((size_t)img << 20));

    if (tid < 2) {
        float4 ninf4 = make_float4(NINF, NINF, NINF, NINF);
        rowbuf[0][tid * 257] = ninf4;         // [0] and [257] pads
        rowbuf[1][tid * 257] = ninf4;
    }

    // column-validity nibble (cols 6..1017 valid)
    int c0 = tid * 4;
    int cvm = 0;
    #pragma unroll
    for (int j = 0; j < 4; ++j) {
        int cc = c0 + j;
        if (cc >= 6 && cc <= 1017) cvm |= (1 << j);
    }

    // rolling window: slot(input row r0+j) = (j+3)&7 ; preload j=-3..3
    float4 w[8];
    #pragma unroll
    for (int k = 0; k < 7; ++k) {
        int rr = r0 - 3 + k;
        w[k] = (rr >= 0) ? base[rr * 256 + tid] : make_float4(NINF, NINF, NINF, NINF);
    }

    int cnt = 0;
    #pragma unroll 1
    for (int ii = 0; ii < 2; ++ii) {
        #pragma unroll
        for (int jj = 0; jj < 8; ++jj) {
            int gh = r0 + ii * 8 + jj;
            // prefetch input row gh+4 into slot (jj+7)&7 (used next iteration)
            {
                int lr = gh + 4;
                w[(jj + 7) & 7] = (lr <= 1023) ? base[lr * 256 + tid]
                                               : make_float4(NINF, NINF, NINF, NINF);
            }
            // vertical 7-max over slots jj..jj+6
            float4 s0 = w[(jj + 0) & 7], s1 = w[(jj + 1) & 7], s2 = w[(jj + 2) & 7];
            float4 s3 = w[(jj + 3) & 7], s4 = w[(jj + 4) & 7], s5 = w[(jj + 5) & 7];
            float4 s6 = w[(jj + 6) & 7];
            float4 vm;
            vm.x = max3f(max3f(s0.x, s1.x, s2.x), max3f(s3.x, s4.x, s5.x), s6.x);
            vm.y = max3f(max3f(s0.y, s1.y, s2.y), max3f(s3.y, s4.y, s5.y), s6.y);
            vm.z = max3f(max3f(s0.z, s1.z, s2.z), max3f(s3.z, s4.z, s5.z), s6.z);
            vm.w = max3f(max3f(s0.w, s1.w, s2.w), max3f(s3.w, s4.w, s5.w), s6.w);

            rowbuf[jj & 1][tid + 1] = vm;
            __syncthreads();
            float4 L = rowbuf[jj & 1][tid];
            float4 R = rowbuf[jj & 1][tid + 2];

            // horizontal 7-max for cols 4t..4t+3
            float m0 = max3f(max3f(L.y, L.z, L.w),  max3f(vm.x, vm.y, vm.z), vm.w);
            float m1 = max3f(max3f(L.z, L.w, vm.x), max3f(vm.y, vm.z, vm.w), R.x);
            float m2 = max3f(max3f(L.w, vm.x, vm.y), max3f(vm.z, vm.w, R.x), R.y);
            float m3 = max3f(max3f(vm.x, vm.y, vm.z), max3f(vm.w, R.x, R.y), R.z);

            float4 ctr = s3;                   // original row gh (slot jj+3)
            int rowok = (gh >= 6) & (gh <= 1017);
            int f0 = (ctr.x == m0) & (ctr.x > 0.5f) & ((cvm >> 0) & 1) & rowok;
            int f1 = (ctr.y == m1) & (ctr.y > 0.5f) & ((cvm >> 1) & 1) & rowok;
            int f2 = (ctr.z == m2) & (ctr.z > 0.5f) & ((cvm >> 2) & 1) & rowok;
            int f3 = (ctr.w == m3) & (ctr.w > 0.5f) & ((cvm >> 3) & 1) & rowok;
            cnt += f0 + f1 + f2 + f3;

            unsigned long long B0 = __ballot(f0);
            unsigned long long B1 = __ballot(f1);
            unsigned long long B2 = __ballot(f2);
            unsigned long long B3 = __ballot(f3);
            if (lane < 4) {
                unsigned long long word =  spread4(B0 >> (16 * lane))
                                        | (spread4(B1 >> (16 * lane)) << 1)
                                        | (spread4(B2 >> (16 * lane)) << 2)
                                        | (spread4(B3 >> (16 * lane)) << 3);
                // word index: img*16384 + gh*16 + (wv*4 + lane)
                bits[((size_t)img << 14) + ((size_t)gh << 4) + (wv * 4 + lane)] = word;
            }
        }
    }

    // per-chunk count (chunk == this block's stripe)
    for (int off = 32; off; off >>= 1) cnt += __shfl_down(cnt, off, 64);
    if (lane == 0) sred[wv] = cnt;
    __syncthreads();
    if (tid == 0) chunkCount[(img << 6) + stripe] = (unsigned)(sred[0] + sred[1] + sred[2] + sred[3]);
}

// ---- B: fused scan + ordered scatter (float32 outputs) ----
// block = b*128 + chunk_in_batch; 256 threads, one u64 word each
__global__ __launch_bounds__(256) void scan_scatter(const float* __restrict__ map,
                                                    const unsigned long long* __restrict__ bits,
                                                    const unsigned* __restrict__ chunkCount,
                                                    float* __restrict__ out) {
    int blk = blockIdx.x;
    int b = blk >> 7, cib = blk & 127;
    int tid = threadIdx.x;
    int lane = tid & 63, wv = tid >> 6;

    __shared__ unsigned sw[4];
    __shared__ unsigned sbase;
    __shared__ int wsum[4];

    // chunk base = sum of counts of earlier chunks in this batch
    unsigned v = (tid < cib) ? chunkCount[b * 128 + tid] : 0u;   // tid>=128 -> tid>=cib -> 0
    for (int off = 32; off; off >>= 1) v += __shfl_down(v, off, 64);
    if (lane == 0) sw[wv] = v;
    __syncthreads();
    if (tid == 0) sbase = sw[0] + sw[1] + sw[2] + sw[3];

    // own word + intra-block exclusive prefix of popcounts (shfl scan)
    unsigned long long wd = bits[(size_t)blk * 256 + tid];
    int cnt = __popcll(wd);
    int incl = cnt;
    #pragma unroll
    for (int off = 1; off < 64; off <<= 1) {
        int n = __shfl_up(incl, off, 64);
        if (lane >= off) incl += n;
    }
    if (lane == 63) wsum[wv] = incl;
    __syncthreads();

    int wpre = 0;
    #pragma unroll
    for (int k = 0; k < 4; ++k) if (k < wv) wpre += wsum[k];
    unsigned base = sbase + (unsigned)wpre + (unsigned)(incl - cnt);
    unsigned wib = ((unsigned)cib) * 256u + (unsigned)tid;       // word idx in batch

    unsigned long long m = wd;
    unsigned n = 0;
    while (m) {
        int bit = __builtin_ctzll(m);
        m &= m - 1;
        unsigned slot = base + n;
        n++;
        if (slot < MAXP) {
            unsigned flat = wib * 64u + (unsigned)bit;   // < 2^21
            unsigned c = flat >> 20;
            unsigned h = (flat >> 10) & 1023u;
            unsigned w = flat & 1023u;
            float score = map[(size_t)b * CHW + flat];
            unsigned o = b * MAXP + slot;
            out[2u * o]         = (float)w;              // x
            out[2u * o + 1]     = (float)h;              // y
            out[LABEL_OFF + o]  = (float)(c + 1u);       // label
            out[SCORE_OFF + o]  = score;                 // score
        }
    }
}

extern "C" void kernel_launch(void* const* d_in, const int* in_sizes, int n_in,
                              void* d_out, int out_size, void* d_ws, size_t ws_size,
                              hipStream_t stream) {
    const float* map = (const float*)d_in[0];
    float* out = (float*)d_out;
    unsigned long long* bits = (unsigned long long*)d_ws;        // 262144 u64 = 2 MB
    unsigned* chunkCount = (unsigned*)((char*)d_ws + 2097152);   // 1024 u32

    fused_mask<<<3072, 256, 0, stream>>>(map, bits, chunkCount, out);
    scan_scatter<<<1024, 256, 0, stream>>>(map, bits, chunkCount, out);
}

// Round 5
// 35.378 us; speedup vs baseline: 2.0817x; 1.1735x over previous
//
#include <hip/hip_runtime.h>

#define HW  (1024u*1024u)
#define CHW (2u*HW)
#define MAXP 65536u
#define LABEL_OFF 1048576u
#define SCORE_OFF 1572864u
#define NINF (-3.0e38f)

__device__ __forceinline__ float max3f(float a, float b, float c) {
    return fmaxf(fmaxf(a, b), c);
}

// ---- A: fused 7x7 NMS mask (32-row stripes, pair rows) + per-chunk count + out fill ----
// blocks 0..511: mask (img = bid>>5, stripe = bid&31, 32 rows each)
// blocks 512..2559: fill d_out (coords=-1, labels/scores=0)
__global__ __launch_bounds__(256) void fused_mask(const float* __restrict__ map,
                                                  unsigned long long* __restrict__ bits,
                                                  unsigned* __restrict__ chunkCount,
                                                  float* __restrict__ out) {
    int bid = blockIdx.x;
    int tid = threadIdx.x;

    if (bid >= 512) {                          // ---- fill part ----
        int i = (bid - 512) * 256 + tid;
        float v = (i < 262144) ? -1.0f : 0.0f; // 262144 float4 = coords region
        float4 f; f.x = f.y = f.z = f.w = v;
        ((float4*)out)[i] = f;
        return;
    }

    // ---- mask part ----
    __shared__ float4 rowbuf[2][2][258];       // [parity][rowInPair][col4+pads]
    __shared__ unsigned sred[4];
    int stripe = bid & 31;
    int img = bid >> 5;                        // b*2 + c
    int r0 = stripe << 5;
    int lane = tid & 63, wv = tid >> 6;
    const float4* __restrict__ base = (const float4*)(map + ((size_t)img << 20));

    if (tid < 8) {                             // NINF pads at [*][*][0] and [*][*][257]
        float4 n4 = make_float4(NINF, NINF, NINF, NINF);
        rowbuf[(tid >> 2) & 1][(tid >> 1) & 1][(tid & 1) * 257] = n4;
    }

    // column-validity nibble (cols 6..1017 valid)
    int c0 = tid * 4;
    int cvm = 0;
    #pragma unroll
    for (int j = 0; j < 4; ++j) {
        int cc = c0 + j;
        if (cc >= 6 && cc <= 1017) cvm |= (1 << j);
    }

    // rolling 10-slot window: input row q -> slot (q - r0 + 3) mod 10
    float4 w[10];
    #pragma unroll
    for (int k = 0; k < 8; ++k) {
        int rr = r0 - 3 + k;
        w[k] = ((unsigned)rr < 1024u) ? base[rr * 256 + tid]
                                      : make_float4(NINF, NINF, NINF, NINF);
    }

    unsigned cnt01 = 0;    // low16: rows r0..r0+15 (chunk0), high16: rows r0+16..r0+31

    #pragma unroll
    for (int p = 0; p < 16; ++p) {             // pair rows rA = r0+2p, rB = rA+1
        int rA = r0 + 2 * p;
        if (p < 15) {                           // prefetch rows rA+5, rA+6
            int q1 = rA + 5, q2 = rA + 6;
            w[(2 * p + 8) % 10] = ((unsigned)q1 < 1024u) ? base[q1 * 256 + tid]
                                                         : make_float4(NINF, NINF, NINF, NINF);
            w[(2 * p + 9) % 10] = ((unsigned)q2 < 1024u) ? base[q2 * 256 + tid]
                                                         : make_float4(NINF, NINF, NINF, NINF);
        }
        float4 s0 = w[(2 * p + 0) % 10], s1 = w[(2 * p + 1) % 10];
        float4 s2 = w[(2 * p + 2) % 10], s3 = w[(2 * p + 3) % 10];
        float4 s4 = w[(2 * p + 4) % 10], s5 = w[(2 * p + 5) % 10];
        float4 s6 = w[(2 * p + 6) % 10], s7 = w[(2 * p + 7) % 10];

        // vertical: common6 = max(rows rA-2..rA+3); vmA = max(c6, rA-3); vmB = max(c6, rA+4)
        float4 c6, vmA, vmB;
        c6.x = fmaxf(max3f(s1.x, s2.x, s3.x), max3f(s4.x, s5.x, s6.x));
        c6.y = fmaxf(max3f(s1.y, s2.y, s3.y), max3f(s4.y, s5.y, s6.y));
        c6.z = fmaxf(max3f(s1.z, s2.z, s3.z), max3f(s4.z, s5.z, s6.z));
        c6.w = fmaxf(max3f(s1.w, s2.w, s3.w), max3f(s4.w, s5.w, s6.w));
        vmA.x = fmaxf(c6.x, s0.x); vmB.x = fmaxf(c6.x, s7.x);
        vmA.y = fmaxf(c6.y, s0.y); vmB.y = fmaxf(c6.y, s7.y);
        vmA.z = fmaxf(c6.z, s0.z); vmB.z = fmaxf(c6.z, s7.z);
        vmA.w = fmaxf(c6.w, s0.w); vmB.w = fmaxf(c6.w, s7.w);

        rowbuf[p & 1][0][tid + 1] = vmA;
        rowbuf[p & 1][1][tid + 1] = vmB;
        __syncthreads();
        float4 LA = rowbuf[p & 1][0][tid], RA = rowbuf[p & 1][0][tid + 2];
        float4 LB = rowbuf[p & 1][1][tid], RB = rowbuf[p & 1][1][tid + 2];

        // horizontal 7-max
        float mA0 = max3f(max3f(LA.y, LA.z, LA.w),  max3f(vmA.x, vmA.y, vmA.z), vmA.w);
        float mA1 = max3f(max3f(LA.z, LA.w, vmA.x), max3f(vmA.y, vmA.z, vmA.w), RA.x);
        float mA2 = max3f(max3f(LA.w, vmA.x, vmA.y), max3f(vmA.z, vmA.w, RA.x), RA.y);
        float mA3 = max3f(max3f(vmA.x, vmA.y, vmA.z), max3f(vmA.w, RA.x, RA.y), RA.z);
        float mB0 = max3f(max3f(LB.y, LB.z, LB.w),  max3f(vmB.x, vmB.y, vmB.z), vmB.w);
        float mB1 = max3f(max3f(LB.z, LB.w, vmB.x), max3f(vmB.y, vmB.z, vmB.w), RB.x);
        float mB2 = max3f(max3f(LB.w, vmB.x, vmB.y), max3f(vmB.z, vmB.w, RB.x), RB.y);
        float mB3 = max3f(max3f(vmB.x, vmB.y, vmB.z), max3f(vmB.w, RB.x, RB.y), RB.z);

        float4 ctrA = s3, ctrB = s4;            // original rows rA, rB
        int fA0 = (ctrA.x == mA0) & (ctrA.x > 0.5f);
        int fA1 = (ctrA.y == mA1) & (ctrA.y > 0.5f);
        int fA2 = (ctrA.z == mA2) & (ctrA.z > 0.5f);
        int fA3 = (ctrA.w == mA3) & (ctrA.w > 0.5f);
        int fB0 = (ctrB.x == mB0) & (ctrB.x > 0.5f);
        int fB1 = (ctrB.y == mB1) & (ctrB.y > 0.5f);
        int fB2 = (ctrB.z == mB2) & (ctrB.z > 0.5f);
        int fB3 = (ctrB.w == mB3) & (ctrB.w > 0.5f);
        int nibA = (fA0 | (fA1 << 1) | (fA2 << 2) | (fA3 << 3)) & cvm;
        int nibB = (fB0 | (fB1 << 1) | (fB2 << 2) | (fB3 << 3)) & cvm;
        int rowokA = (rA >= 6) & (rA <= 1017);
        int rowokB = ((rA + 1) >= 6) & ((rA + 1) <= 1017);
        nibA = rowokA ? nibA : 0;
        nibB = rowokB ? nibB : 0;

        unsigned pc = (unsigned)(__popc((unsigned)nibA) + __popc((unsigned)nibB));
        cnt01 += (p < 8) ? pc : (pc << 16);

        // assemble u64 words: nibble j of word = lane (16g+j) in wave
        unsigned long long vA = ((unsigned long long)(unsigned)nibA) << ((lane & 15) * 4);
        unsigned long long vB = ((unsigned long long)(unsigned)nibB) << ((lane & 15) * 4);
        vA |= __shfl_xor(vA, 1, 64); vB |= __shfl_xor(vB, 1, 64);
        vA |= __shfl_xor(vA, 2, 64); vB |= __shfl_xor(vB, 2, 64);
        vA |= __shfl_xor(vA, 4, 64); vB |= __shfl_xor(vB, 4, 64);
        vA |= __shfl_xor(vA, 8, 64); vB |= __shfl_xor(vB, 8, 64);
        if ((lane & 15) == 0) {
            size_t wbase = ((size_t)img << 14) + ((size_t)rA << 4) + 4 * wv + (lane >> 4);
            bits[wbase]      = vA;
            bits[wbase + 16] = vB;              // row rA+1
        }
    }

    // per-chunk counts (this block = 2 chunks of 16 rows)
    for (int off = 32; off; off >>= 1) cnt01 += __shfl_down(cnt01, off, 64);
    if (lane == 0) sred[wv] = cnt01;
    __syncthreads();
    if (tid == 0) {
        unsigned tot = sred[0] + sred[1] + sred[2] + sred[3];
        int b = img >> 1, c = img & 1;
        unsigned cidx = (unsigned)(b * 128 + c * 64 + stripe * 2);
        chunkCount[cidx]     = tot & 0xFFFFu;
        chunkCount[cidx + 1] = tot >> 16;
    }
}

// ---- B: fused scan + ordered scatter (float32 outputs) ----
// block = b*128 + chunk_in_batch; 256 threads, one u64 word each
__global__ __launch_bounds__(256) void scan_scatter(const float* __restrict__ map,
                                                    const unsigned long long* __restrict__ bits,
                                                    const unsigned* __restrict__ chunkCount,
                                                    float* __restrict__ out) {
    int blk = blockIdx.x;
    int b = blk >> 7, cib = blk & 127;
    int tid = threadIdx.x;
    int lane = tid & 63, wv = tid >> 6;

    __shared__ unsigned sw[4];
    __shared__ unsigned sbase;
    __shared__ int wsum[4];

    // chunk base = sum of counts of earlier chunks in this batch
    unsigned v = (tid < cib) ? chunkCount[b * 128 + tid] : 0u;
    for (int off = 32; off; off >>= 1) v += __shfl_down(v, off, 64);
    if (lane == 0) sw[wv] = v;
    __syncthreads();
    if (tid == 0) sbase = sw[0] + sw[1] + sw[2] + sw[3];

    // own word + intra-block exclusive prefix of popcounts (shfl scan)
    unsigned long long wd = bits[(size_t)blk * 256 + tid];
    int cnt = __popcll(wd);
    int incl = cnt;
    #pragma unroll
    for (int off = 1; off < 64; off <<= 1) {
        int n = __shfl_up(incl, off, 64);
        if (lane >= off) incl += n;
    }
    if (lane == 63) wsum[wv] = incl;
    __syncthreads();

    int wpre = 0;
    #pragma unroll
    for (int k = 0; k < 4; ++k) if (k < wv) wpre += wsum[k];
    unsigned base = sbase + (unsigned)wpre + (unsigned)(incl - cnt);
    unsigned wib = ((unsigned)cib) * 256u + (unsigned)tid;       // word idx in batch

    unsigned long long m = wd;
    unsigned n = 0;
    while (m) {
        int bit = __builtin_ctzll(m);
        m &= m - 1;
        unsigned slot = base + n;
        n++;
        if (slot < MAXP) {
            unsigned flat = wib * 64u + (unsigned)bit;   // < 2^21
            unsigned c = flat >> 20;
            unsigned h = (flat >> 10) & 1023u;
            unsigned w = flat & 1023u;
            float score = map[(size_t)b * CHW + flat];
            unsigned o = b * MAXP + slot;
            out[2u * o]         = (float)w;              // x
            out[2u * o + 1]     = (float)h;              // y
            out[LABEL_OFF + o]  = (float)(c + 1u);       // label
            out[SCORE_OFF + o]  = score;                 // score
        }
    }
}

extern "C" void kernel_launch(void* const* d_in, const int* in_sizes, int n_in,
                              void* d_out, int out_size, void* d_ws, size_t ws_size,
                              hipStream_t stream) {
    const float* map = (const float*)d_in[0];
    float* out = (float*)d_out;
    unsigned long long* bits = (unsigned long long*)d_ws;        // 262144 u64 = 2 MB
    unsigned* chunkCount = (unsigned*)((char*)d_ws + 2097152);   // 1024 u32

    fused_mask<<<2560, 256, 0, stream>>>(map, bits, chunkCount, out);
    scan_scatter<<<1024, 256, 0, stream>>>(map, bits, chunkCount, out);
}

// Round 6
// 34.073 us; speedup vs baseline: 2.1614x; 1.0383x over previous
//
#include <hip/hip_runtime.h>

#define HW  (1024u*1024u)
#define CHW (2u*HW)
#define MAXP 65536u
#define LABEL_OFF 1048576u
#define SCORE_OFF 1572864u
#define NINF (-3.0e38f)

__device__ __forceinline__ float max3f(float a, float b, float c) {
    return fmaxf(fmaxf(a, b), c);
}

// ---- A: 7x7 NMS mask + per-chunk count ----
// 1024 blocks, XCD-swizzled; block = one 16-row stripe of one image = one chunk
__global__ __launch_bounds__(256, 4) void mask_kernel(const float* __restrict__ map,
                                                      unsigned long long* __restrict__ bits,
                                                      unsigned* __restrict__ chunkCount) {
    __shared__ float4 rowbuf[2][2][258];       // [parity][rowInPair][col4+pads]
    __shared__ unsigned sred[4];
    int bid0 = blockIdx.x;
    int bid = (bid0 & 7) * 128 + (bid0 >> 3);  // XCD swizzle (bijective: 1024 % 8 == 0)
    int tid = threadIdx.x;
    int stripe = bid & 63;
    int img = bid >> 6;                        // b*2 + c
    int r0 = stripe << 4;
    int lane = tid & 63, wv = tid >> 6;
    const float4* __restrict__ base = (const float4*)(map + ((size_t)img << 20));

    if (tid < 8) {                             // NINF pads at [*][*][0] and [*][*][257]
        float4 n4 = make_float4(NINF, NINF, NINF, NINF);
        rowbuf[(tid >> 2) & 1][(tid >> 1) & 1][(tid & 1) * 257] = n4;
    }

    // column-validity nibble (cols 6..1017 valid)
    int c0 = tid * 4;
    int cvm = 0;
    #pragma unroll
    for (int j = 0; j < 4; ++j) {
        int cc = c0 + j;
        if (cc >= 6 && cc <= 1017) cvm |= (1 << j);
    }

    // rolling 10-slot window: input row q -> slot (q - r0 + 3) mod 10
    float4 w[10];
    #pragma unroll
    for (int k = 0; k < 8; ++k) {
        int rr = r0 - 3 + k;
        w[k] = ((unsigned)rr < 1024u) ? base[rr * 256 + tid]
                                      : make_float4(NINF, NINF, NINF, NINF);
    }

    unsigned cnt = 0;

    #pragma unroll
    for (int p = 0; p < 8; ++p) {              // pair rows rA = r0+2p, rB = rA+1
        int rA = r0 + 2 * p;
        if (p < 7) {                           // prefetch rows rA+5, rA+6
            int q1 = rA + 5, q2 = rA + 6;
            w[(2 * p + 8) % 10] = ((unsigned)q1 < 1024u) ? base[q1 * 256 + tid]
                                                         : make_float4(NINF, NINF, NINF, NINF);
            w[(2 * p + 9) % 10] = ((unsigned)q2 < 1024u) ? base[q2 * 256 + tid]
                                                         : make_float4(NINF, NINF, NINF, NINF);
        }
        float4 s0 = w[(2 * p + 0) % 10], s1 = w[(2 * p + 1) % 10];
        float4 s2 = w[(2 * p + 2) % 10], s3 = w[(2 * p + 3) % 10];
        float4 s4 = w[(2 * p + 4) % 10], s5 = w[(2 * p + 5) % 10];
        float4 s6 = w[(2 * p + 6) % 10], s7 = w[(2 * p + 7) % 10];

        // vertical: common6 = max(rows rA-2..rA+3); vmA = max(c6, rA-3); vmB = max(c6, rA+4)
        float4 c6, vmA, vmB;
        c6.x = fmaxf(max3f(s1.x, s2.x, s3.x), max3f(s4.x, s5.x, s6.x));
        c6.y = fmaxf(max3f(s1.y, s2.y, s3.y), max3f(s4.y, s5.y, s6.y));
        c6.z = fmaxf(max3f(s1.z, s2.z, s3.z), max3f(s4.z, s5.z, s6.z));
        c6.w = fmaxf(max3f(s1.w, s2.w, s3.w), max3f(s4.w, s5.w, s6.w));
        vmA.x = fmaxf(c6.x, s0.x); vmB.x = fmaxf(c6.x, s7.x);
        vmA.y = fmaxf(c6.y, s0.y); vmB.y = fmaxf(c6.y, s7.y);
        vmA.z = fmaxf(c6.z, s0.z); vmB.z = fmaxf(c6.z, s7.z);
        vmA.w = fmaxf(c6.w, s0.w); vmB.w = fmaxf(c6.w, s7.w);

        rowbuf[p & 1][0][tid + 1] = vmA;
        rowbuf[p & 1][1][tid + 1] = vmB;
        __syncthreads();
        float4 LA = rowbuf[p & 1][0][tid], RA = rowbuf[p & 1][0][tid + 2];
        float4 LB = rowbuf[p & 1][1][tid], RB = rowbuf[p & 1][1][tid + 2];

        // horizontal 7-max
        float mA0 = max3f(max3f(LA.y, LA.z, LA.w),  max3f(vmA.x, vmA.y, vmA.z), vmA.w);
        float mA1 = max3f(max3f(LA.z, LA.w, vmA.x), max3f(vmA.y, vmA.z, vmA.w), RA.x);
        float mA2 = max3f(max3f(LA.w, vmA.x, vmA.y), max3f(vmA.z, vmA.w, RA.x), RA.y);
        float mA3 = max3f(max3f(vmA.x, vmA.y, vmA.z), max3f(vmA.w, RA.x, RA.y), RA.z);
        float mB0 = max3f(max3f(LB.y, LB.z, LB.w),  max3f(vmB.x, vmB.y, vmB.z), vmB.w);
        float mB1 = max3f(max3f(LB.z, LB.w, vmB.x), max3f(vmB.y, vmB.z, vmB.w), RB.x);
        float mB2 = max3f(max3f(LB.w, vmB.x, vmB.y), max3f(vmB.z, vmB.w, RB.x), RB.y);
        float mB3 = max3f(max3f(vmB.x, vmB.y, vmB.z), max3f(vmB.w, RB.x, RB.y), RB.z);

        float4 ctrA = s3, ctrB = s4;            // original rows rA, rB
        int fA0 = (ctrA.x == mA0) & (ctrA.x > 0.5f);
        int fA1 = (ctrA.y == mA1) & (ctrA.y > 0.5f);
        int fA2 = (ctrA.z == mA2) & (ctrA.z > 0.5f);
        int fA3 = (ctrA.w == mA3) & (ctrA.w > 0.5f);
        int fB0 = (ctrB.x == mB0) & (ctrB.x > 0.5f);
        int fB1 = (ctrB.y == mB1) & (ctrB.y > 0.5f);
        int fB2 = (ctrB.z == mB2) & (ctrB.z > 0.5f);
        int fB3 = (ctrB.w == mB3) & (ctrB.w > 0.5f);
        int nibA = (fA0 | (fA1 << 1) | (fA2 << 2) | (fA3 << 3)) & cvm;
        int nibB = (fB0 | (fB1 << 1) | (fB2 << 2) | (fB3 << 3)) & cvm;
        int rowokA = (rA >= 6) & (rA <= 1017);
        int rowokB = ((rA + 1) >= 6) & ((rA + 1) <= 1017);
        nibA = rowokA ? nibA : 0;
        nibB = rowokB ? nibB : 0;

        cnt += (unsigned)(__popc((unsigned)nibA) + __popc((unsigned)nibB));

        // assemble u64 words: nibble j of word = lane (16g+j) in wave
        unsigned long long vA = ((unsigned long long)(unsigned)nibA) << ((lane & 15) * 4);
        unsigned long long vB = ((unsigned long long)(unsigned)nibB) << ((lane & 15) * 4);
        vA |= __shfl_xor(vA, 1, 64); vB |= __shfl_xor(vB, 1, 64);
        vA |= __shfl_xor(vA, 2, 64); vB |= __shfl_xor(vB, 2, 64);
        vA |= __shfl_xor(vA, 4, 64); vB |= __shfl_xor(vB, 4, 64);
        vA |= __shfl_xor(vA, 8, 64); vB |= __shfl_xor(vB, 8, 64);
        if ((lane & 15) == 0) {
            size_t wbase = ((size_t)img << 14) + ((size_t)rA << 4) + 4 * wv + (lane >> 4);
            bits[wbase]      = vA;
            bits[wbase + 16] = vB;              // row rA+1
        }
    }

    // per-chunk count (block == one chunk)
    for (int off = 32; off; off >>= 1) cnt += __shfl_down(cnt, off, 64);
    if (lane == 0) sred[wv] = cnt;
    __syncthreads();
    if (tid == 0) chunkCount[(img << 6) + stripe] = sred[0] + sred[1] + sred[2] + sred[3];
}

// ---- B: fused scan + ordered scatter + tail padding (float32 outputs) ----
// block = b*128 + chunk_in_batch; 256 threads, one u64 word each
__global__ __launch_bounds__(256) void scan_scatter(const float* __restrict__ map,
                                                    const unsigned long long* __restrict__ bits,
                                                    const unsigned* __restrict__ chunkCount,
                                                    float* __restrict__ out) {
    int blk = blockIdx.x;
    int b = blk >> 7, cib = blk & 127;
    int tid = threadIdx.x;
    int lane = tid & 63, wv = tid >> 6;

    __shared__ unsigned long long sw[4];
    __shared__ unsigned sbase, stotal;
    __shared__ int wsum[4];

    // packed reduce: low32 = sum over chunks < cib (base), high32 = sum over all (total)
    unsigned cc = (tid < 128) ? chunkCount[b * 128 + tid] : 0u;
    unsigned long long v = ((tid < cib) ? (unsigned long long)cc : 0ull)
                         | ((unsigned long long)cc << 32);
    for (int off = 32; off; off >>= 1) v += __shfl_down(v, off, 64);
    if (lane == 0) sw[wv] = v;
    __syncthreads();
    if (tid == 0) {
        unsigned long long t = sw[0] + sw[1] + sw[2] + sw[3];
        sbase  = (unsigned)t;
        stotal = (unsigned)(t >> 32);
    }

    // own word + intra-block exclusive prefix of popcounts (shfl scan)
    unsigned long long wd = bits[(size_t)blk * 256 + tid];
    int cnt = __popcll(wd);
    int incl = cnt;
    #pragma unroll
    for (int off = 1; off < 64; off <<= 1) {
        int n = __shfl_up(incl, off, 64);
        if (lane >= off) incl += n;
    }
    if (lane == 63) wsum[wv] = incl;
    __syncthreads();                            // also publishes sbase/stotal

    int wpre = 0;
    #pragma unroll
    for (int k = 0; k < 4; ++k) if (k < wv) wpre += wsum[k];
    unsigned base = sbase + (unsigned)wpre + (unsigned)(incl - cnt);
    unsigned wib = ((unsigned)cib) * 256u + (unsigned)tid;       // word idx in batch

    unsigned long long m = wd;
    unsigned n = 0;
    while (m) {
        int bit = __builtin_ctzll(m);
        m &= m - 1;
        unsigned slot = base + n;
        n++;
        if (slot < MAXP) {
            unsigned flat = wib * 64u + (unsigned)bit;   // < 2^21
            unsigned c = flat >> 20;
            unsigned h = (flat >> 10) & 1023u;
            unsigned w = flat & 1023u;
            float score = map[(size_t)b * CHW + flat];
            unsigned o = b * MAXP + slot;
            out[2u * o]         = (float)w;              // x
            out[2u * o + 1]     = (float)h;              // y
            out[LABEL_OFF + o]  = (float)(c + 1u);       // label
            out[SCORE_OFF + o]  = score;                 // score
        }
    }

    // tail padding: this block owns slots [cib*512, cib*512+512)
    unsigned total = stotal;
    #pragma unroll
    for (int k = 0; k < 2; ++k) {
        unsigned slot = ((unsigned)cib) * 512u + (unsigned)tid + (unsigned)k * 256u;
        if (slot >= total) {                    // slot < 65536 by construction
            unsigned o = b * MAXP + slot;
            float2 neg1; neg1.x = -1.0f; neg1.y = -1.0f;
            ((float2*)out)[o]   = neg1;          // coords (x,y) = -1
            out[LABEL_OFF + o]  = 0.0f;
            out[SCORE_OFF + o]  = 0.0f;
        }
    }
}

extern "C" void kernel_launch(void* const* d_in, const int* in_sizes, int n_in,
                              void* d_out, int out_size, void* d_ws, size_t ws_size,
                              hipStream_t stream) {
    const float* map = (const float*)d_in[0];
    float* out = (float*)d_out;
    unsigned long long* bits = (unsigned long long*)d_ws;        // 262144 u64 = 2 MB
    unsigned* chunkCount = (unsigned*)((char*)d_ws + 2097152);   // 1024 u32

    mask_kernel<<<1024, 256, 0, stream>>>(map, bits, chunkCount);
    scan_scatter<<<1024, 256, 0, stream>>>(map, bits, chunkCount, out);
}

// Round 7
// 33.099 us; speedup vs baseline: 2.2251x; 1.0294x over previous
//
#include <hip/hip_runtime.h>

#define HW  (1024u*1024u)
#define CHW (2u*HW)
#define MAXP 65536u
#define LABEL_OFF 1048576u
#define SCORE_OFF 1572864u
#define NINF (-3.0e38f)

__device__ __forceinline__ float max3f(float a, float b, float c) {
    return fmaxf(fmaxf(a, b), c);
}

// ---- A: 7x7 NMS mask + per-chunk count ----
// 1024 blocks, XCD-swizzled; block = one 16-row stripe of one image = one chunk
// rolling 12-slot register window, prefetch depth = 2 pair-iterations
__global__ __launch_bounds__(256, 4) void mask_kernel(const float* __restrict__ map,
                                                      unsigned* __restrict__ bits32,
                                                      unsigned* __restrict__ chunkCount) {
    __shared__ float4 rowbuf[2][2][258];       // [parity][rowInPair][col4+pads]
    __shared__ unsigned sred[4];
    int bid0 = blockIdx.x;
    int bid = (bid0 & 7) * 128 + (bid0 >> 3);  // XCD swizzle (bijective: 1024 % 8 == 0)
    int tid = threadIdx.x;
    int stripe = bid & 63;
    int img = bid >> 6;                        // b*2 + c
    int r0 = stripe << 4;
    int lane = tid & 63, wv = tid >> 6;
    const float4* __restrict__ base = (const float4*)(map + ((size_t)img << 20));

    if (tid < 8) {                             // NINF pads at [*][*][0] and [*][*][257]
        float4 n4 = make_float4(NINF, NINF, NINF, NINF);
        rowbuf[(tid >> 2) & 1][(tid >> 1) & 1][(tid & 1) * 257] = n4;
    }

    // column-validity nibble (cols 6..1017 valid)
    int c0 = tid * 4;
    int cvm = 0;
    #pragma unroll
    for (int j = 0; j < 4; ++j) {
        int cc = c0 + j;
        if (cc >= 6 && cc <= 1017) cvm |= (1 << j);
    }

    // rolling 12-slot window: input row q -> slot (q - r0 + 3) mod 12
    float4 w[12];
    #pragma unroll
    for (int k = 0; k < 10; ++k) {             // rows r0-3 .. r0+6
        int rr = r0 - 3 + k;
        w[k] = ((unsigned)rr < 1024u) ? base[rr * 256 + tid]
                                      : make_float4(NINF, NINF, NINF, NINF);
    }

    unsigned cnt = 0;

    #pragma unroll
    for (int p = 0; p < 8; ++p) {              // pair rows rA = r0+2p, rB = rA+1
        int rA = r0 + 2 * p;
        if (p < 6) {                           // prefetch rows rA+7, rA+8 (for iter p+2)
            int q1 = rA + 7, q2 = rA + 8;
            w[(2 * p + 10) % 12] = ((unsigned)q1 < 1024u) ? base[q1 * 256 + tid]
                                                          : make_float4(NINF, NINF, NINF, NINF);
            w[(2 * p + 11) % 12] = ((unsigned)q2 < 1024u) ? base[q2 * 256 + tid]
                                                          : make_float4(NINF, NINF, NINF, NINF);
        }
        float4 s0 = w[(2 * p + 0) % 12], s1 = w[(2 * p + 1) % 12];
        float4 s2 = w[(2 * p + 2) % 12], s3 = w[(2 * p + 3) % 12];
        float4 s4 = w[(2 * p + 4) % 12], s5 = w[(2 * p + 5) % 12];
        float4 s6 = w[(2 * p + 6) % 12], s7 = w[(2 * p + 7) % 12];

        // vertical: common6 = max(rows rA-2..rA+3); vmA = max(c6, rA-3); vmB = max(c6, rA+4)
        float4 c6, vmA, vmB;
        c6.x = fmaxf(max3f(s1.x, s2.x, s3.x), max3f(s4.x, s5.x, s6.x));
        c6.y = fmaxf(max3f(s1.y, s2.y, s3.y), max3f(s4.y, s5.y, s6.y));
        c6.z = fmaxf(max3f(s1.z, s2.z, s3.z), max3f(s4.z, s5.z, s6.z));
        c6.w = fmaxf(max3f(s1.w, s2.w, s3.w), max3f(s4.w, s5.w, s6.w));
        vmA.x = fmaxf(c6.x, s0.x); vmB.x = fmaxf(c6.x, s7.x);
        vmA.y = fmaxf(c6.y, s0.y); vmB.y = fmaxf(c6.y, s7.y);
        vmA.z = fmaxf(c6.z, s0.z); vmB.z = fmaxf(c6.z, s7.z);
        vmA.w = fmaxf(c6.w, s0.w); vmB.w = fmaxf(c6.w, s7.w);

        rowbuf[p & 1][0][tid + 1] = vmA;
        rowbuf[p & 1][1][tid + 1] = vmB;
        __syncthreads();
        float4 LA = rowbuf[p & 1][0][tid], RA = rowbuf[p & 1][0][tid + 2];
        float4 LB = rowbuf[p & 1][1][tid], RB = rowbuf[p & 1][1][tid + 2];

        // horizontal 7-max
        float mA0 = max3f(max3f(LA.y, LA.z, LA.w),  max3f(vmA.x, vmA.y, vmA.z), vmA.w);
        float mA1 = max3f(max3f(LA.z, LA.w, vmA.x), max3f(vmA.y, vmA.z, vmA.w), RA.x);
        float mA2 = max3f(max3f(LA.w, vmA.x, vmA.y), max3f(vmA.z, vmA.w, RA.x), RA.y);
        float mA3 = max3f(max3f(vmA.x, vmA.y, vmA.z), max3f(vmA.w, RA.x, RA.y), RA.z);
        float mB0 = max3f(max3f(LB.y, LB.z, LB.w),  max3f(vmB.x, vmB.y, vmB.z), vmB.w);
        float mB1 = max3f(max3f(LB.z, LB.w, vmB.x), max3f(vmB.y, vmB.z, vmB.w), RB.x);
        float mB2 = max3f(max3f(LB.w, vmB.x, vmB.y), max3f(vmB.z, vmB.w, RB.x), RB.y);
        float mB3 = max3f(max3f(vmB.x, vmB.y, vmB.z), max3f(vmB.w, RB.x, RB.y), RB.z);

        float4 ctrA = s3, ctrB = s4;            // original rows rA, rB
        int fA0 = (ctrA.x == mA0) & (ctrA.x > 0.5f);
        int fA1 = (ctrA.y == mA1) & (ctrA.y > 0.5f);
        int fA2 = (ctrA.z == mA2) & (ctrA.z > 0.5f);
        int fA3 = (ctrA.w == mA3) & (ctrA.w > 0.5f);
        int fB0 = (ctrB.x == mB0) & (ctrB.x > 0.5f);
        int fB1 = (ctrB.y == mB1) & (ctrB.y > 0.5f);
        int fB2 = (ctrB.z == mB2) & (ctrB.z > 0.5f);
        int fB3 = (ctrB.w == mB3) & (ctrB.w > 0.5f);
        int nibA = (fA0 | (fA1 << 1) | (fA2 << 2) | (fA3 << 3)) & cvm;
        int nibB = (fB0 | (fB1 << 1) | (fB2 << 2) | (fB3 << 3)) & cvm;
        int rowokA = (rA >= 6) & (rA <= 1017);
        int rowokB = ((rA + 1) >= 6) & ((rA + 1) <= 1017);
        nibA = rowokA ? nibA : 0;
        nibB = rowokB ? nibB : 0;

        cnt += (unsigned)(__popc((unsigned)nibA) + __popc((unsigned)nibB));

        // assemble u32 half-words: 8-lane group g = lanes 8g..8g+7 -> cols 32g..32g+31
        // bit (4*(lane&7)+j) of the group's u32 = nib bit j
        unsigned vA = (unsigned)nibA << ((lane & 7) * 4);
        unsigned vB = (unsigned)nibB << ((lane & 7) * 4);
        vA |= __shfl_xor(vA, 1, 64); vB |= __shfl_xor(vB, 1, 64);
        vA |= __shfl_xor(vA, 2, 64); vB |= __shfl_xor(vB, 2, 64);
        vA |= __shfl_xor(vA, 4, 64); vB |= __shfl_xor(vB, 4, 64);
        if ((lane & 7) == 0) {
            // u32 index = img*32768 + row*32 + wv*8 + (lane>>3)
            size_t wbase = ((size_t)img << 15) + ((size_t)rA << 5) + wv * 8 + (lane >> 3);
            bits32[wbase]      = vA;
            bits32[wbase + 32] = vB;            // row rA+1
        }
    }

    // per-chunk count (block == one chunk)
    for (int off = 32; off; off >>= 1) cnt += __shfl_down(cnt, off, 64);
    if (lane == 0) sred[wv] = cnt;
    __syncthreads();
    if (tid == 0) chunkCount[(img << 6) + stripe] = sred[0] + sred[1] + sred[2] + sred[3];
}

// ---- B: fused scan + ordered scatter + tail padding (float32 outputs) ----
// block = b*128 + chunk_in_batch; 256 threads, one u64 word each
__global__ __launch_bounds__(256) void scan_scatter(const float* __restrict__ map,
                                                    const unsigned long long* __restrict__ bits,
                                                    const unsigned* __restrict__ chunkCount,
                                                    float* __restrict__ out) {
    int blk = blockIdx.x;
    int b = blk >> 7, cib = blk & 127;
    int tid = threadIdx.x;
    int lane = tid & 63, wv = tid >> 6;

    __shared__ unsigned long long sw[4];
    __shared__ unsigned sbase, stotal;
    __shared__ int wsum[4];

    // packed reduce: low32 = sum over chunks < cib (base), high32 = sum over all (total)
    unsigned cc = (tid < 128) ? chunkCount[b * 128 + tid] : 0u;
    unsigned long long v = ((tid < cib) ? (unsigned long long)cc : 0ull)
                         | ((unsigned long long)cc << 32);
    for (int off = 32; off; off >>= 1) v += __shfl_down(v, off, 64);
    if (lane == 0) sw[wv] = v;
    __syncthreads();
    if (tid == 0) {
        unsigned long long t = sw[0] + sw[1] + sw[2] + sw[3];
        sbase  = (unsigned)t;
        stotal = (unsigned)(t >> 32);
    }

    // own word + intra-block exclusive prefix of popcounts (shfl scan)
    unsigned long long wd = bits[(size_t)blk * 256 + tid];
    int cnt = __popcll(wd);
    int incl = cnt;
    #pragma unroll
    for (int off = 1; off < 64; off <<= 1) {
        int n = __shfl_up(incl, off, 64);
        if (lane >= off) incl += n;
    }
    if (lane == 63) wsum[wv] = incl;
    __syncthreads();                            // also publishes sbase/stotal

    int wpre = 0;
    #pragma unroll
    for (int k = 0; k < 4; ++k) if (k < wv) wpre += wsum[k];
    unsigned base = sbase + (unsigned)wpre + (unsigned)(incl - cnt);
    unsigned wib = ((unsigned)cib) * 256u + (unsigned)tid;       // word idx in batch

    unsigned long long m = wd;
    unsigned n = 0;
    while (m) {
        int bit = __builtin_ctzll(m);
        m &= m - 1;
        unsigned slot = base + n;
        n++;
        if (slot < MAXP) {
            unsigned flat = wib * 64u + (unsigned)bit;   // < 2^21
            unsigned c = flat >> 20;
            unsigned h = (flat >> 10) & 1023u;
            unsigned w = flat & 1023u;
            float score = map[(size_t)b * CHW + flat];
            unsigned o = b * MAXP + slot;
            out[2u * o]         = (float)w;              // x
            out[2u * o + 1]     = (float)h;              // y
            out[LABEL_OFF + o]  = (float)(c + 1u);       // label
            out[SCORE_OFF + o]  = score;                 // score
        }
    }

    // tail padding: this block owns slots [cib*512, cib*512+512)
    unsigned total = stotal;
    #pragma unroll
    for (int k = 0; k < 2; ++k) {
        unsigned slot = ((unsigned)cib) * 512u + (unsigned)tid + (unsigned)k * 256u;
        if (slot >= total) {                    // slot < 65536 by construction
            unsigned o = b * MAXP + slot;
            float2 neg1; neg1.x = -1.0f; neg1.y = -1.0f;
            ((float2*)out)[o]   = neg1;          // coords (x,y) = -1
            out[LABEL_OFF + o]  = 0.0f;
            out[SCORE_OFF + o]  = 0.0f;
        }
    }
}

extern "C" void kernel_launch(void* const* d_in, const int* in_sizes, int n_in,
                              void* d_out, int out_size, void* d_ws, size_t ws_size,
                              hipStream_t stream) {
    const float* map = (const float*)d_in[0];
    float* out = (float*)d_out;
    unsigned long long* bits = (unsigned long long*)d_ws;        // 262144 u64 = 2 MB
    unsigned* chunkCount = (unsigned*)((char*)d_ws + 2097152);   // 1024 u32

    mask_kernel<<<1024, 256, 0, stream>>>(map, (unsigned*)d_ws, chunkCount);
    scan_scatter<<<1024, 256, 0, stream>>>(map, bits, chunkCount, out);
}